// Round 1
// baseline (560.461 us; speedup 1.0000x reference)
//
#include <hip/hip_runtime.h>
#include <math.h>

// NetVLAD forward, fp32 baseline.
// B=32, M=2048, D=1024, K=64.
// pass1: per 64-row m-tile: fused row-sumsq (inv_norm) + logits GEMM (x·W^T) + softmax -> a, a_sum
// pass2: per (b, 64-wide d-tile): vlad GEMM (a^T · x_n) - a_sum*centroids -> d_out (raw), rowsq
// pass3: out *= 1/(max(||row||,eps) * ||v||), where ||v||^2 = sum_k rowsq_k/max(||row_k||,eps)^2

#define NB 32
#define NM 2048
#define ND 1024
#define NK 64

static constexpr float EPS_ = 1e-12f;

// ---------------- pass 1: logits + softmax ----------------
__global__ __launch_bounds__(256) void nv1_logits_softmax(
    const float* __restrict__ x, const float* __restrict__ W,
    float* __restrict__ a, float* __restrict__ invn, float* __restrict__ asum)
{
    const int b   = blockIdx.y;
    const int mt  = blockIdx.x;      // 32 m-tiles of 64 rows
    const int tid = threadIdx.x;
    const int tk  = tid & 15;        // micro-tile col group (k)
    const int tm  = tid >> 4;        // micro-tile row group (m)
    const int r0  = tid >> 3;        // staging row 0..31
    const int c0  = (tid & 7) << 2;  // staging col 0,4,...,28

    // transposed chunks: [d within chunk][row], stride 68 keeps 16B alignment for b128 reads
    __shared__ float Xs[32][68];
    __shared__ float Ws[32][68];
    __shared__ float red[64][8];
    __shared__ float inv_l[64];
    __shared__ float asum_l[64];

    float acc[4][4] = {};
    float sq0 = 0.f, sq1 = 0.f;

    const float* xb = x + ((size_t)b * NM + (size_t)mt * 64) * ND;

    for (int d0 = 0; d0 < ND; d0 += 32) {
        __syncthreads();
        const float4 xv0 = *(const float4*)(xb + (size_t)r0 * ND + d0 + c0);
        const float4 xv1 = *(const float4*)(xb + (size_t)(r0 + 32) * ND + d0 + c0);
        const float4 wv0 = *(const float4*)(W + (size_t)r0 * ND + d0 + c0);
        const float4 wv1 = *(const float4*)(W + (size_t)(r0 + 32) * ND + d0 + c0);
        // fused row-sumsq for inv_norm (each thread always stages the same two rows)
        sq0 += xv0.x*xv0.x + xv0.y*xv0.y + xv0.z*xv0.z + xv0.w*xv0.w;
        sq1 += xv1.x*xv1.x + xv1.y*xv1.y + xv1.z*xv1.z + xv1.w*xv1.w;
        Xs[c0+0][r0]    = xv0.x; Xs[c0+1][r0]    = xv0.y; Xs[c0+2][r0]    = xv0.z; Xs[c0+3][r0]    = xv0.w;
        Xs[c0+0][r0+32] = xv1.x; Xs[c0+1][r0+32] = xv1.y; Xs[c0+2][r0+32] = xv1.z; Xs[c0+3][r0+32] = xv1.w;
        Ws[c0+0][r0]    = wv0.x; Ws[c0+1][r0]    = wv0.y; Ws[c0+2][r0]    = wv0.z; Ws[c0+3][r0]    = wv0.w;
        Ws[c0+0][r0+32] = wv1.x; Ws[c0+1][r0+32] = wv1.y; Ws[c0+2][r0+32] = wv1.z; Ws[c0+3][r0+32] = wv1.w;
        __syncthreads();
        #pragma unroll
        for (int dk = 0; dk < 32; ++dk) {
            const float4 xm = *(const float4*)&Xs[dk][tm << 2];
            const float4 wk = *(const float4*)&Ws[dk][tk << 2];
            const float xa[4] = {xm.x, xm.y, xm.z, xm.w};
            const float wa[4] = {wk.x, wk.y, wk.z, wk.w};
            #pragma unroll
            for (int i = 0; i < 4; ++i)
                #pragma unroll
                for (int j = 0; j < 4; ++j)
                    acc[i][j] = fmaf(xa[i], wa[j], acc[i][j]);
        }
    }

    // combine 8 per-row sumsq partials -> inv_norm
    red[r0][tid & 7]      = sq0;
    red[r0 + 32][tid & 7] = sq1;
    __syncthreads();
    if (tid < 64) {
        float s = 0.f;
        #pragma unroll
        for (int i = 0; i < 8; ++i) s += red[tid][i];
        const float iv = 1.f / fmaxf(sqrtf(s), EPS_);
        inv_l[tid] = iv;
        invn[(size_t)b * NM + (size_t)mt * 64 + tid] = iv;
        asum_l[tid] = 0.f;
    }
    __syncthreads();

    // softmax over k (64 values live in 16 lanes x 4 regs, same 16-lane group)
    float asp[4] = {0.f, 0.f, 0.f, 0.f};
    #pragma unroll
    for (int i = 0; i < 4; ++i) {
        const int m = (tm << 2) + i;
        const float iv = inv_l[m];
        float l0 = acc[i][0] * iv, l1 = acc[i][1] * iv, l2 = acc[i][2] * iv, l3 = acc[i][3] * iv;
        float mx = fmaxf(fmaxf(l0, l1), fmaxf(l2, l3));
        #pragma unroll
        for (int s = 1; s < 16; s <<= 1) mx = fmaxf(mx, __shfl_xor(mx, s, 64));
        float e0 = __expf(l0 - mx), e1 = __expf(l1 - mx), e2 = __expf(l2 - mx), e3 = __expf(l3 - mx);
        float sm = e0 + e1 + e2 + e3;
        #pragma unroll
        for (int s = 1; s < 16; s <<= 1) sm += __shfl_xor(sm, s, 64);
        const float rs = 1.f / sm;
        e0 *= rs; e1 *= rs; e2 *= rs; e3 *= rs;
        *(float4*)(a + ((size_t)b * NM + (size_t)mt * 64 + m) * NK + (tk << 2)) = make_float4(e0, e1, e2, e3);
        asp[0] += e0; asp[1] += e1; asp[2] += e2; asp[3] += e3;
    }
    #pragma unroll
    for (int j = 0; j < 4; ++j) atomicAdd(&asum_l[(tk << 2) + j], asp[j]);
    __syncthreads();
    if (tid < 64) atomicAdd(&asum[b * NK + tid], asum_l[tid]);
}

// ---------------- pass 2: vlad = a^T x_n - a_sum*centroids ----------------
__global__ __launch_bounds__(256) void nv2_vlad(
    const float* __restrict__ x, const float* __restrict__ a,
    const float* __restrict__ invn, const float* __restrict__ asum,
    const float* __restrict__ cent, float* __restrict__ out, float* __restrict__ rowsq)
{
    const int b   = blockIdx.y;
    const int dt  = blockIdx.x;      // 16 tiles of 64 d-columns
    const int tid = threadIdx.x;
    const int td  = tid & 15;        // micro-tile col group (d)
    const int tkk = tid >> 4;        // micro-tile row group (k)

    // natural layout: reduction dim (m) is the slab row, so reads are k/d-contiguous
    __shared__ float As[32][68];
    __shared__ float Xs[32][68];
    __shared__ float rsq_l[64];

    float acc[4][4] = {};

    const int rr = tid >> 4;         // staging row 0..15 (+16)
    const int cc = (tid & 15) << 2;  // staging col 0..60

    for (int ch = 0; ch < NM / 32; ++ch) {
        const int m0 = ch * 32;
        __syncthreads();
        #pragma unroll
        for (int p = 0; p < 2; ++p) {
            const int ml = rr + 16 * p;
            const size_t mg = (size_t)b * NM + m0 + ml;
            const float4 av = *(const float4*)(a + mg * NK + cc);
            const float iv = invn[mg];
            float4 xv = *(const float4*)(x + mg * ND + (size_t)dt * 64 + cc);
            xv.x *= iv; xv.y *= iv; xv.z *= iv; xv.w *= iv;
            *(float4*)&As[ml][cc] = av;
            *(float4*)&Xs[ml][cc] = xv;
        }
        __syncthreads();
        #pragma unroll
        for (int m = 0; m < 32; ++m) {
            const float4 am = *(const float4*)&As[m][tkk << 2];
            const float4 xm = *(const float4*)&Xs[m][td << 2];
            const float aa[4] = {am.x, am.y, am.z, am.w};
            const float xx[4] = {xm.x, xm.y, xm.z, xm.w};
            #pragma unroll
            for (int i = 0; i < 4; ++i)
                #pragma unroll
                for (int j = 0; j < 4; ++j)
                    acc[i][j] = fmaf(aa[i], xx[j], acc[i][j]);
        }
    }

    if (tid < 64) rsq_l[tid] = 0.f;
    __syncthreads();

    #pragma unroll
    for (int i = 0; i < 4; ++i) {
        const int k = (tkk << 2) + i;
        const float as = asum[b * NK + k];
        const float4 cv = *(const float4*)(cent + (size_t)k * ND + (size_t)dt * 64 + (td << 2));
        const float v0 = acc[i][0] - as * cv.x;
        const float v1 = acc[i][1] - as * cv.y;
        const float v2 = acc[i][2] - as * cv.z;
        const float v3 = acc[i][3] - as * cv.w;
        *(float4*)(out + ((size_t)b * NK + k) * ND + (size_t)dt * 64 + (td << 2)) =
            make_float4(v0, v1, v2, v3);
        atomicAdd(&rsq_l[k], v0*v0 + v1*v1 + v2*v2 + v3*v3);
    }
    __syncthreads();
    if (tid < 64) atomicAdd(&rowsq[b * NK + tid], rsq_l[tid]);
}

// ---------------- pass 3: intra + global normalize (in place) ----------------
__global__ __launch_bounds__(256) void nv3_norm(
    float* __restrict__ out, const float* __restrict__ rowsq)
{
    const int b   = blockIdx.y;
    const int ck  = blockIdx.x;      // 16 chunks of 4096 elements
    const int tid = threadIdx.x;
    __shared__ float rinv[64];
    __shared__ float gred[64];
    __shared__ float ginv_s;
    if (tid < 64) {
        const float rs = rowsq[b * NK + tid];
        const float n  = fmaxf(sqrtf(rs), EPS_);
        rinv[tid] = 1.f / n;
        gred[tid] = (rs / n) / n;    // ||v_k||^2 after intra-normalization
    }
    __syncthreads();
    if (tid == 0) {
        float s = 0.f;
        for (int k = 0; k < 64; ++k) s += gred[k];
        ginv_s = 1.f / fmaxf(sqrtf(s), EPS_);
    }
    __syncthreads();
    const float gi = ginv_s;
    float* ob = out + (size_t)b * (NK * ND);
    #pragma unroll
    for (int it = 0; it < 4; ++it) {
        const int idx = ck * 4096 + it * 1024 + tid * 4;   // one k-row per iteration
        const float sc = rinv[idx >> 10] * gi;
        float4 v = *(float4*)(ob + idx);
        v.x *= sc; v.y *= sc; v.z *= sc; v.w *= sc;
        *(float4*)(ob + idx) = v;
    }
}

extern "C" void kernel_launch(void* const* d_in, const int* in_sizes, int n_in,
                              void* d_out, int out_size, void* d_ws, size_t ws_size,
                              hipStream_t stream)
{
    const float* x    = (const float*)d_in[0];
    const float* W    = (const float*)d_in[1];
    const float* cent = (const float*)d_in[2];
    float* out = (float*)d_out;

    // workspace layout
    const size_t A_BYTES = (size_t)NB * NM * NK * sizeof(float);   // 16 MiB soft-assignments
    const size_t I_BYTES = (size_t)NB * NM * sizeof(float);        // 256 KiB inv_norm
    float* a     = (float*)d_ws;
    float* invn  = (float*)((char*)d_ws + A_BYTES);
    float* asum  = (float*)((char*)d_ws + A_BYTES + I_BYTES);
    float* rowsq = asum + NB * NK;

    // asum & rowsq are atomically accumulated -> zero them (ws is poisoned 0xAA)
    hipMemsetAsync(asum, 0, 2 * NB * NK * sizeof(float), stream);

    nv1_logits_softmax<<<dim3(NM / 64, NB), 256, 0, stream>>>(x, W, a, invn, asum);
    nv2_vlad<<<dim3(ND / 64, NB), 256, 0, stream>>>(x, a, invn, asum, cent, out, rowsq);
    nv3_norm<<<dim3(16, NB), 256, 0, stream>>>(out, rowsq);
}

// Round 2
// 447.003 us; speedup vs baseline: 1.2538x; 1.2538x over previous
//
#include <hip/hip_runtime.h>
#include <math.h>

// NetVLAD forward, bf16-MFMA version. B=32, M=2048, D=1024, K=64.
// nv1: per (b, 64-row m-tile): fused sumsq + bf16 MFMA logits + softmax
//      -> a' = softmax * invn, bf16, stored PRE-SUBTILED (4x16 subtiles, col-major grid)
//      -> asum (fp32 global atomics)
// nv2: per (b, 128-wide d-tile): vlad = a'^T · bf16(x_raw) via MFMA with
//      ds_read_b64_tr_b16 fragments; minus asum*centroids; writes out + rowsq.
// nv3: intra + global normalize in place.

#define NB 32
#define NM 2048
#define ND 1024
#define NK 64

typedef float f32x4 __attribute__((ext_vector_type(4)));
typedef short s16x4 __attribute__((ext_vector_type(4)));
typedef short s16x8 __attribute__((ext_vector_type(8)));

static constexpr float EPS_ = 1e-12f;

__device__ __forceinline__ short f2bf(float f) {
    union { float f; unsigned u; } v; v.f = f;
    unsigned r = v.u + 0x7fffu + ((v.u >> 16) & 1u);   // RNE
    return (short)(r >> 16);
}

// ---------------- pass 1: logits (MFMA) + softmax -> a' (subtiled bf16), asum ----------------
__global__ __launch_bounds__(256) void nv1_logits_softmax(
    const float* __restrict__ x, const float* __restrict__ W,
    short* __restrict__ aT, float* __restrict__ asum)
{
    const int b = blockIdx.y, mt = blockIdx.x;
    const int tid  = threadIdx.x;
    const int w    = tid >> 6, lane = tid & 63, g = lane >> 4, c = lane & 15;
    const int wm   = w >> 1, wk = w & 1;

    __shared__ union {
        struct { short Xs[64][72]; short Ws[64][72]; } st;   // 18432 B
        float Ls[64][68];                                    // 17408 B
    } sm;
    __shared__ float red[64][16];
    __shared__ float inv_l[64];
    __shared__ float asum_l[64];

    f32x4 acc[2][2] = {};
    float sq[4] = {0.f, 0.f, 0.f, 0.f};

    const int sr = tid >> 4;      // staging row group 0..15
    const int sc = tid & 15;      // staging col group (x4 floats)
    const float* xb = x + ((size_t)b * NM + (size_t)mt * 64) * ND;

    for (int d0 = 0; d0 < ND; d0 += 64) {
        __syncthreads();
        #pragma unroll
        for (int i = 0; i < 4; ++i) {
            const int r = sr + 16 * i;
            const float4 xv = *(const float4*)(xb + (size_t)r * ND + d0 + sc * 4);
            const float4 wv = *(const float4*)(W  + (size_t)r * ND + d0 + sc * 4);
            sq[i] += xv.x*xv.x + xv.y*xv.y + xv.z*xv.z + xv.w*xv.w;
            s16x4 xh, wh;
            xh[0]=f2bf(xv.x); xh[1]=f2bf(xv.y); xh[2]=f2bf(xv.z); xh[3]=f2bf(xv.w);
            wh[0]=f2bf(wv.x); wh[1]=f2bf(wv.y); wh[2]=f2bf(wv.z); wh[3]=f2bf(wv.w);
            *(s16x4*)&sm.st.Xs[r][sc * 4] = xh;
            *(s16x4*)&sm.st.Ws[r][sc * 4] = wh;
        }
        __syncthreads();
        #pragma unroll
        for (int s = 0; s < 2; ++s) {
            s16x8 af[2], bf[2];
            #pragma unroll
            for (int f = 0; f < 2; ++f) {
                af[f] = *(const s16x8*)&sm.st.Xs[wm*32 + f*16 + c][s*32 + g*8];
                bf[f] = *(const s16x8*)&sm.st.Ws[wk*32 + f*16 + c][s*32 + g*8];
            }
            #pragma unroll
            for (int fm = 0; fm < 2; ++fm)
                #pragma unroll
                for (int fk = 0; fk < 2; ++fk)
                    acc[fm][fk] = __builtin_amdgcn_mfma_f32_16x16x32_bf16(
                        af[fm], bf[fk], acc[fm][fk], 0, 0, 0);
        }
    }
    __syncthreads();
    // row-sumsq partials + logits to LDS (union region: X/W reads are done)
    #pragma unroll
    for (int i = 0; i < 4; ++i) red[sr + 16*i][sc] = sq[i];
    #pragma unroll
    for (int fm = 0; fm < 2; ++fm)
        #pragma unroll
        for (int fk = 0; fk < 2; ++fk)
            #pragma unroll
            for (int r = 0; r < 4; ++r)
                sm.Ls[wm*32 + fm*16 + g*4 + r][wk*32 + fk*16 + c] = acc[fm][fk][r];
    __syncthreads();
    if (tid < 64) {
        float s = 0.f;
        #pragma unroll
        for (int i = 0; i < 16; ++i) s += red[tid][i];
        inv_l[tid]  = 1.f / fmaxf(sqrtf(s), EPS_);
        asum_l[tid] = 0.f;
    }
    __syncthreads();

    // softmax: thread -> (row = tid>>2, 16 k's). Row spread over 4 consecutive lanes.
    const int row = tid >> 2, q = tid & 3;
    const float iv = inv_l[row];
    float e[16];
    float mx = -3.0e38f;
    #pragma unroll
    for (int j = 0; j < 16; ++j) { e[j] = sm.Ls[row][q*16 + j] * iv; mx = fmaxf(mx, e[j]); }
    mx = fmaxf(mx, __shfl_xor(mx, 1, 64));
    mx = fmaxf(mx, __shfl_xor(mx, 2, 64));
    float smv = 0.f;
    #pragma unroll
    for (int j = 0; j < 16; ++j) { e[j] = __expf(e[j] - mx); smv += e[j]; }
    smv += __shfl_xor(smv, 1, 64);
    smv += __shfl_xor(smv, 2, 64);
    const float rs = 1.f / smv;
    #pragma unroll
    for (int j = 0; j < 16; ++j) e[j] *= rs;     // plain softmax a

    // a' = a * invn, bf16, pre-subtiled: elem((m,k)) = (( (k>>4)*16 + (m>>2) )*64 + (m&3)*16 + (k&15))
    alignas(16) short av[16];
    #pragma unroll
    for (int j = 0; j < 16; ++j) av[j] = f2bf(e[j] * iv);
    {
        const size_t base = ((size_t)(b * 32 + mt)) * 4096
                          + (size_t)(q * 16 + (row >> 2)) * 64 + (size_t)(row & 3) * 16;
        *(int4*)(aT + base)     = *(int4*)&av[0];
        *(int4*)(aT + base + 8) = *(int4*)&av[8];
    }
    // asum: reduce plain a over rows (shfl over row bits), then LDS + global atomics
    #pragma unroll
    for (int msk = 4; msk <= 32; msk <<= 1)
        #pragma unroll
        for (int j = 0; j < 16; ++j) e[j] += __shfl_xor(e[j], msk, 64);
    if ((tid & 60) == 0)
        #pragma unroll
        for (int j = 0; j < 16; ++j) atomicAdd(&asum_l[q*16 + j], e[j]);
    __syncthreads();
    if (tid < 64) atomicAdd(asum + b * 64 + tid, asum_l[tid]);
}

// ---------------- pass 2: vlad = a'^T x_raw (MFMA, tr_b16 frags) - asum*cent ----------------
__global__ __launch_bounds__(512) void nv2_vlad(
    const float* __restrict__ x, const short* __restrict__ aT,
    const float* __restrict__ asum, const float* __restrict__ cent,
    float* __restrict__ out, float* __restrict__ rowsq)
{
    const int b = blockIdx.y, dt = blockIdx.x;       // 8 d-tiles of 128
    const int tid  = threadIdx.x;
    const int w    = tid >> 6, lane = tid & 63, g = lane >> 4, c = lane & 15;
    const int wk   = w >> 2, wd = w & 3;             // 2 (k) x 4 (d) wave grid

    __shared__ short Xl[2][8704];    // 8 SCOL x 16 SROW x 68 (subtile stride padded 64->68)
    __shared__ short Al[2][4352];    // 4 SCOL x 16 SROW x 68
    __shared__ float rsq_l[64];

    if (tid < 64) rsq_l[tid] = 0.f;

    f32x4 acc[2][2] = {};

    const int mt_ = tid >> 5;        // 0..15
    const int dq  = tid & 31;        // 0..31 (x4 floats -> 128 d)
    const float* xg = x + (size_t)b * NM * ND + (size_t)dt * 128;

    const uint32_t xbase = (uint32_t)(uintptr_t)&Xl[0][0];
    const uint32_t abase = (uint32_t)(uintptr_t)&Al[0][0];

    float4 xr[4]; int4 ar;

    auto LOAD = [&](int mc) {
        const float* xp = xg + (size_t)mc * 64 * ND;
        #pragma unroll
        for (int i = 0; i < 4; ++i)
            xr[i] = *(const float4*)(xp + (size_t)(mt_ + 16*i) * ND + dq * 4);
        ar = *(const int4*)(aT + ((size_t)(b * 32 + mc)) * 4096 + tid * 8);
    };
    auto WRITE = [&](int p) {
        #pragma unroll
        for (int i = 0; i < 4; ++i) {
            const int m = mt_ + 16 * i;
            s16x4 h;
            h[0]=f2bf(xr[i].x); h[1]=f2bf(xr[i].y); h[2]=f2bf(xr[i].z); h[3]=f2bf(xr[i].w);
            *(s16x4*)&Xl[p][((dq>>2)*16 + (m>>2))*68 + (m&3)*16 + (dq&3)*4] = h;
        }
        const int e0 = tid * 8, idx = e0 >> 6, wo = e0 & 63;
        *(int2*)&Al[p][idx*68 + wo]     = make_int2(ar.x, ar.y);
        *(int2*)&Al[p][idx*68 + wo + 4] = make_int2(ar.z, ar.w);
    };
    auto COMPUTE = [&](int p) {
        const uint32_t xb_ = xbase + (uint32_t)p * 8704u * 2u;
        const uint32_t ab_ = abase + (uint32_t)p * 4352u * 2u;
        s16x4 A[2][2][2], B[2][2][2];    // [frag][kstep][half]
        #pragma unroll
        for (int f = 0; f < 2; ++f)
            #pragma unroll
            for (int s = 0; s < 2; ++s)
                #pragma unroll
                for (int r = 0; r < 2; ++r) {
                    const uint32_t srow = (uint32_t)(s*8 + g*2 + r);
                    const uint32_t aoff = ab_ + (((uint32_t)(wk*2 + f)*16u + srow)*68u)*2u + (uint32_t)c*8u;
                    const uint32_t boff = xb_ + (((uint32_t)(wd*2 + f)*16u + srow)*68u)*2u + (uint32_t)c*8u;
                    asm volatile("ds_read_b64_tr_b16 %0, %1" : "=v"(A[f][s][r]) : "v"(aoff));
                    asm volatile("ds_read_b64_tr_b16 %0, %1" : "=v"(B[f][s][r]) : "v"(boff));
                }
        asm volatile("s_waitcnt lgkmcnt(0)" ::: "memory");
        __builtin_amdgcn_sched_barrier(0);
        #pragma unroll
        for (int s = 0; s < 2; ++s)
            #pragma unroll
            for (int fk = 0; fk < 2; ++fk) {
                const s16x8 af = __builtin_shufflevector(A[fk][s][0], A[fk][s][1], 0,1,2,3,4,5,6,7);
                #pragma unroll
                for (int fd = 0; fd < 2; ++fd) {
                    const s16x8 bf = __builtin_shufflevector(B[fd][s][0], B[fd][s][1], 0,1,2,3,4,5,6,7);
                    acc[fk][fd] = __builtin_amdgcn_mfma_f32_16x16x32_bf16(af, bf, acc[fk][fd], 0, 0, 0);
                }
            }
    };

    LOAD(0); WRITE(0);
    __syncthreads();
    int p = 0;
    for (int mc = 0; mc < 32; ++mc) {
        if (mc < 31) LOAD(mc + 1);   // issue-early (T14): HBM latency hides under compute
        COMPUTE(p);
        if (mc < 31) WRITE(p ^ 1);   // write-late into the other buffer
        __syncthreads();
        p ^= 1;
    }

    // epilogue: subtract asum*cent, write out, accumulate rowsq
    const float* cb = cent + (size_t)dt * 128;
    #pragma unroll
    for (int fk = 0; fk < 2; ++fk)
        #pragma unroll
        for (int r = 0; r < 4; ++r) {
            const int k = wk*32 + fk*16 + g*4 + r;
            const float as = asum[b * 64 + k];
            float s2 = 0.f;
            #pragma unroll
            for (int fd = 0; fd < 2; ++fd) {
                const int d = wd*32 + fd*16 + c;
                const float v = acc[fk][fd][r] - as * cb[(size_t)k * ND + d];
                out[((size_t)b * 64 + k) * ND + (size_t)dt * 128 + d] = v;
                s2 += v * v;
            }
            s2 += __shfl_xor(s2, 1, 64);
            s2 += __shfl_xor(s2, 2, 64);
            s2 += __shfl_xor(s2, 4, 64);
            s2 += __shfl_xor(s2, 8, 64);
            if (c == 0) atomicAdd(&rsq_l[k], s2);
        }
    __syncthreads();
    if (tid < 64) atomicAdd(rowsq + b * 64 + tid, rsq_l[tid]);
}

// ---------------- pass 3: intra + global normalize (in place) ----------------
__global__ __launch_bounds__(256) void nv3_norm(
    float* __restrict__ out, const float* __restrict__ rowsq)
{
    const int b = blockIdx.y, ck = blockIdx.x;
    const int tid = threadIdx.x;
    __shared__ float rinv[64];
    __shared__ float gred[64];
    __shared__ float ginv_s;
    if (tid < 64) {
        const float rs = rowsq[b * NK + tid];
        const float n  = fmaxf(sqrtf(rs), EPS_);
        rinv[tid] = 1.f / n;
        gred[tid] = (rs / n) / n;
    }
    __syncthreads();
    if (tid == 0) {
        float s = 0.f;
        for (int k = 0; k < 64; ++k) s += gred[k];
        ginv_s = 1.f / fmaxf(sqrtf(s), EPS_);
    }
    __syncthreads();
    const float gi = ginv_s;
    float* ob = out + (size_t)b * (NK * ND);
    #pragma unroll
    for (int it = 0; it < 4; ++it) {
        const int idx = ck * 4096 + it * 1024 + tid * 4;
        const float sc = rinv[idx >> 10] * gi;
        float4 v = *(float4*)(ob + idx);
        v.x *= sc; v.y *= sc; v.z *= sc; v.w *= sc;
        *(float4*)(ob + idx) = v;
    }
}

extern "C" void kernel_launch(void* const* d_in, const int* in_sizes, int n_in,
                              void* d_out, int out_size, void* d_ws, size_t ws_size,
                              hipStream_t stream)
{
    const float* x    = (const float*)d_in[0];
    const float* W    = (const float*)d_in[1];
    const float* cent = (const float*)d_in[2];
    float* out = (float*)d_out;

    // ws layout: a' bf16 subtiled (8 MiB) | asum (8 KiB) | rowsq (8 KiB)
    short* aT    = (short*)d_ws;
    float* asum  = (float*)((char*)d_ws + (size_t)NB * NM * NK * 2);
    float* rowsq = asum + NB * NK;

    hipMemsetAsync(asum, 0, 2 * NB * NK * sizeof(float), stream);

    nv1_logits_softmax<<<dim3(NM / 64, NB), 256, 0, stream>>>(x, W, aT, asum);
    nv2_vlad<<<dim3(ND / 128, NB), 512, 0, stream>>>(x, aT, asum, cent, out, rowsq);
    nv3_norm<<<dim3(16, NB), 256, 0, stream>>>(out, rowsq);
}

// Round 4
// 433.927 us; speedup vs baseline: 1.2916x; 1.0301x over previous
//
#include <hip/hip_runtime.h>
#include <math.h>

// NetVLAD forward, bf16-MFMA, gload_lds pipeline. B=32, M=2048, D=1024, K=64.
// nv1: per (b, 64-row m-tile): fused sumsq + bf16 MFMA logits + softmax
//      -> a' = softmax*invn, bf16, subtiled k-major  (ws, 8 MiB)
//      -> xb16 = bf16(x), subtiled per (b,mc,dt) 8192-elem tiles (ws, 128 MiB)
//      -> asum (fp32 global atomics)
// nv2: per (b, 128-wide d-tile): vlad = a'^T · xb16 via MFMA; staging is
//      identity-copy global_load_lds(16B), triple-buffered, 2-deep counted vmcnt
//      with RAW s_barrier (keeps prefetch loads in flight across barriers).
// nv3: intra + global normalize in place.

#define NB 32
#define NM 2048
#define ND 1024
#define NK 64

typedef float f32x4 __attribute__((ext_vector_type(4)));
typedef short s16x4 __attribute__((ext_vector_type(4)));
typedef short s16x8 __attribute__((ext_vector_type(8)));

static constexpr float EPS_ = 1e-12f;

__device__ __forceinline__ short f2bf(float f) {
    union { float f; unsigned u; } v; v.f = f;
    unsigned r = v.u + 0x7fffu + ((v.u >> 16) & 1u);   // RNE
    return (short)(r >> 16);
}

__device__ __forceinline__ void gload16(const void* g, void* l) {
    __builtin_amdgcn_global_load_lds(
        (const __attribute__((address_space(1))) void*)g,
        (__attribute__((address_space(3))) void*)l, 16, 0, 0);
}

// ---------------- pass 1: logits (MFMA) + softmax -> a', xb16, asum ----------------
__global__ __launch_bounds__(256) void nv1_logits_softmax(
    const float* __restrict__ x, const float* __restrict__ W,
    short* __restrict__ aT, short* __restrict__ xbT, float* __restrict__ asum)
{
    const int b = blockIdx.y, mt = blockIdx.x;
    const int tid  = threadIdx.x;
    const int w    = tid >> 6, lane = tid & 63, g = lane >> 4, c = lane & 15;
    const int wm   = w >> 1, wk = w & 1;

    __shared__ union {
        struct { short Xs[64][72]; short Ws[64][72]; } st;   // 18432 B
        float Ls[64][68];                                    // 17408 B
    } sm;
    __shared__ float red[64][16];
    __shared__ float inv_l[64];
    __shared__ float asum_l[64];

    f32x4 acc[2][2] = {};
    float sq[4] = {0.f, 0.f, 0.f, 0.f};

    const int sr = tid >> 4;      // staging row group 0..15
    const int sc = tid & 15;      // staging col group (x4 floats)
    const float* xb = x + ((size_t)b * NM + (size_t)mt * 64) * ND;

    for (int d0 = 0; d0 < ND; d0 += 64) {
        __syncthreads();
        #pragma unroll
        for (int i = 0; i < 4; ++i) {
            const int r = sr + 16 * i;
            const float4 xv = *(const float4*)(xb + (size_t)r * ND + d0 + sc * 4);
            const float4 wv = *(const float4*)(W  + (size_t)r * ND + d0 + sc * 4);
            sq[i] += xv.x*xv.x + xv.y*xv.y + xv.z*xv.z + xv.w*xv.w;
            s16x4 xh, wh;
            xh[0]=f2bf(xv.x); xh[1]=f2bf(xv.y); xh[2]=f2bf(xv.z); xh[3]=f2bf(xv.w);
            wh[0]=f2bf(wv.x); wh[1]=f2bf(wv.y); wh[2]=f2bf(wv.z); wh[3]=f2bf(wv.w);
            *(s16x4*)&sm.st.Xs[r][sc * 4] = xh;
            *(s16x4*)&sm.st.Ws[r][sc * 4] = wh;
            // xb16 subtiled global store: tile = 8192 shorts (64m x 128d);
            // sub = dblk*16 + mblk, 4x16 row-major inside
            const int dg   = d0 + sc * 4;
            const int dt_  = dg >> 7;
            const int dblk = (dg >> 4) & 7;
            const size_t gp = (((size_t)(b * 32 + mt) * 8 + dt_) << 13)
                            + (size_t)((dblk * 16 + (r >> 2)) * 64 + (r & 3) * 16 + (dg & 15));
            *(s16x4*)(xbT + gp) = xh;
        }
        __syncthreads();
        #pragma unroll
        for (int s = 0; s < 2; ++s) {
            s16x8 af[2], bf[2];
            #pragma unroll
            for (int f = 0; f < 2; ++f) {
                af[f] = *(const s16x8*)&sm.st.Xs[wm*32 + f*16 + c][s*32 + g*8];
                bf[f] = *(const s16x8*)&sm.st.Ws[wk*32 + f*16 + c][s*32 + g*8];
            }
            #pragma unroll
            for (int fm = 0; fm < 2; ++fm)
                #pragma unroll
                for (int fk = 0; fk < 2; ++fk)
                    acc[fm][fk] = __builtin_amdgcn_mfma_f32_16x16x32_bf16(
                        af[fm], bf[fk], acc[fm][fk], 0, 0, 0);
        }
    }
    __syncthreads();
    // row-sumsq partials + logits to LDS (union region: X/W reads are done)
    #pragma unroll
    for (int i = 0; i < 4; ++i) red[sr + 16*i][sc] = sq[i];
    #pragma unroll
    for (int fm = 0; fm < 2; ++fm)
        #pragma unroll
        for (int fk = 0; fk < 2; ++fk)
            #pragma unroll
            for (int r = 0; r < 4; ++r)
                sm.Ls[wm*32 + fm*16 + g*4 + r][wk*32 + fk*16 + c] = acc[fm][fk][r];
    __syncthreads();
    if (tid < 64) {
        float s = 0.f;
        #pragma unroll
        for (int i = 0; i < 16; ++i) s += red[tid][i];
        inv_l[tid]  = 1.f / fmaxf(sqrtf(s), EPS_);
        asum_l[tid] = 0.f;
    }
    __syncthreads();

    // softmax: thread -> (row = tid>>2, 16 k's). Row spread over 4 consecutive lanes.
    const int row = tid >> 2, q = tid & 3;
    const float iv = inv_l[row];
    float e[16];
    float mx = -3.0e38f;
    #pragma unroll
    for (int j = 0; j < 16; ++j) { e[j] = sm.Ls[row][q*16 + j] * iv; mx = fmaxf(mx, e[j]); }
    mx = fmaxf(mx, __shfl_xor(mx, 1, 64));
    mx = fmaxf(mx, __shfl_xor(mx, 2, 64));
    float smv = 0.f;
    #pragma unroll
    for (int j = 0; j < 16; ++j) { e[j] = __expf(e[j] - mx); smv += e[j]; }
    smv += __shfl_xor(smv, 1, 64);
    smv += __shfl_xor(smv, 2, 64);
    const float rs = 1.f / smv;
    #pragma unroll
    for (int j = 0; j < 16; ++j) e[j] *= rs;     // plain softmax a

    // a' = a * invn, bf16, subtiled k-major: sub = (k>>4)*16 + (m>>2)
    alignas(16) short av[16];
    #pragma unroll
    for (int j = 0; j < 16; ++j) av[j] = f2bf(e[j] * iv);
    {
        const size_t base = ((size_t)(b * 32 + mt)) * 4096
                          + (size_t)(q * 16 + (row >> 2)) * 64 + (size_t)(row & 3) * 16;
        *(int4*)(aT + base)     = *(int4*)&av[0];
        *(int4*)(aT + base + 8) = *(int4*)&av[8];
    }
    // asum: reduce plain a over rows (shfl over row bits), then LDS + global atomics
    #pragma unroll
    for (int msk = 4; msk <= 32; msk <<= 1)
        #pragma unroll
        for (int j = 0; j < 16; ++j) e[j] += __shfl_xor(e[j], msk, 64);
    if ((tid & 60) == 0)
        #pragma unroll
        for (int j = 0; j < 16; ++j) atomicAdd(&asum_l[q*16 + j], e[j]);
    __syncthreads();
    if (tid < 64) atomicAdd(asum + b * 64 + tid, asum_l[tid]);
}

// ---------------- pass 2: vlad = a'^T xb16 (MFMA, gload_lds, tri-buffer 2-deep) ----------------
__global__ __launch_bounds__(512) void nv2_vlad(
    const short* __restrict__ xbT, const short* __restrict__ aT,
    const float* __restrict__ asum, const float* __restrict__ cent,
    float* __restrict__ out, float* __restrict__ rowsq)
{
    const int b = blockIdx.y, dt = blockIdx.x;       // 8 d-tiles of 128
    const int tid  = threadIdx.x;
    const int w    = tid >> 6, lane = tid & 63, g = lane >> 4, c = lane & 15;
    const int wk   = w >> 2, wd = w & 3;             // 2 (k) x 4 (d) wave grid

    __shared__ short Xl[3][8192];    // 64m x 128d bf16, linear subtiled (16 KiB each)
    __shared__ short Al[3][4096];    // 64m x 64k  bf16, linear subtiled (8 KiB each)
    __shared__ float rsq_l[64];

    if (tid < 64) rsq_l[tid] = 0.f;

    f32x4 acc[2][2] = {};

    auto STAGE = [&](int mc, int p) {
        const short* xs  = xbT + (((size_t)(b * 32 + mc) * 8 + dt) << 13);
        const short* as_ = aT  + ((size_t)(b * 32 + mc) << 12);
        gload16(xs  + w * 1024 + lane * 8,       &Xl[p][w * 1024]);
        gload16(xs  + w * 1024 + 512 + lane * 8, &Xl[p][w * 1024 + 512]);
        gload16(as_ + w * 512 + lane * 8,        &Al[p][w * 512]);
    };

    auto COMPUTE = [&](int p) {
        const uint32_t ab_ = (uint32_t)(uintptr_t)&Al[p][0];
        const uint32_t xb_ = (uint32_t)(uintptr_t)&Xl[p][0];
        s16x4 A[2][2][2], B[2][2][2];    // [frag][kstep][half]
        #pragma unroll
        for (int f = 0; f < 2; ++f)
            #pragma unroll
            for (int s = 0; s < 2; ++s)
                #pragma unroll
                for (int r = 0; r < 2; ++r) {
                    const uint32_t srow = (uint32_t)(s*8 + g*2 + r);
                    const uint32_t aoff = ab_ + (((uint32_t)(wk*2 + f)*16u + srow)*128u) + (uint32_t)c*8u;
                    const uint32_t boff = xb_ + (((uint32_t)(wd*2 + f)*16u + srow)*128u) + (uint32_t)c*8u;
                    asm volatile("ds_read_b64_tr_b16 %0, %1" : "=v"(A[f][s][r]) : "v"(aoff));
                    asm volatile("ds_read_b64_tr_b16 %0, %1" : "=v"(B[f][s][r]) : "v"(boff));
                }
        asm volatile("s_waitcnt lgkmcnt(0)" ::: "memory");
        __builtin_amdgcn_sched_barrier(0);
        #pragma unroll
        for (int s = 0; s < 2; ++s)
            #pragma unroll
            for (int fk = 0; fk < 2; ++fk) {
                const s16x8 af = __builtin_shufflevector(A[fk][s][0], A[fk][s][1], 0,1,2,3,4,5,6,7);
                #pragma unroll
                for (int fd = 0; fd < 2; ++fd) {
                    const s16x8 bf = __builtin_shufflevector(B[fd][s][0], B[fd][s][1], 0,1,2,3,4,5,6,7);
                    acc[fk][fd] = __builtin_amdgcn_mfma_f32_16x16x32_bf16(af, bf, acc[fk][fd], 0, 0, 0);
                }
            }
    };

    // prologue: fill 2 buffers, keep them in flight (T4: counted vmcnt, raw barrier)
    STAGE(0, 0);
    STAGE(1, 1);
    for (int mc = 0; mc < 32; ++mc) {
        // wait for chunk mc only (3 oldest loads); chunk mc+1's 3 stay in flight
        if (mc < 31) asm volatile("s_waitcnt vmcnt(3)" ::: "memory");
        else         asm volatile("s_waitcnt vmcnt(0)" ::: "memory");
        __builtin_amdgcn_s_barrier();
        if (mc + 2 < 32) STAGE(mc + 2, (mc + 2) % 3);   // after barrier: buffer reuse is race-free
        COMPUTE(mc % 3);
    }

    // epilogue: subtract asum*cent, write out, accumulate rowsq
    const float* cb = cent + (size_t)dt * 128;
    #pragma unroll
    for (int fk = 0; fk < 2; ++fk)
        #pragma unroll
        for (int r = 0; r < 4; ++r) {
            const int k = wk*32 + fk*16 + g*4 + r;
            const float as = asum[b * 64 + k];
            float s2 = 0.f;
            #pragma unroll
            for (int fd = 0; fd < 2; ++fd) {
                const int d = wd*32 + fd*16 + c;
                const float v = acc[fk][fd][r] - as * cb[(size_t)k * ND + d];
                out[((size_t)b * 64 + k) * ND + (size_t)dt * 128 + d] = v;
                s2 += v * v;
            }
            s2 += __shfl_xor(s2, 1, 64);
            s2 += __shfl_xor(s2, 2, 64);
            s2 += __shfl_xor(s2, 4, 64);
            s2 += __shfl_xor(s2, 8, 64);
            if (c == 0) atomicAdd(&rsq_l[k], s2);
        }
    __syncthreads();
    if (tid < 64) atomicAdd(rowsq + b * 64 + tid, rsq_l[tid]);
}

// ---------------- pass 3: intra + global normalize (in place) ----------------
__global__ __launch_bounds__(256) void nv3_norm(
    float* __restrict__ out, const float* __restrict__ rowsq)
{
    const int b = blockIdx.y, ck = blockIdx.x;
    const int tid = threadIdx.x;
    __shared__ float rinv[64];
    __shared__ float gred[64];
    __shared__ float ginv_s;
    if (tid < 64) {
        const float rs = rowsq[b * NK + tid];
        const float n  = fmaxf(sqrtf(rs), EPS_);
        rinv[tid] = 1.f / n;
        gred[tid] = (rs / n) / n;
    }
    __syncthreads();
    if (tid == 0) {
        float s = 0.f;
        for (int k = 0; k < 64; ++k) s += gred[k];
        ginv_s = 1.f / fmaxf(sqrtf(s), EPS_);
    }
    __syncthreads();
    const float gi = ginv_s;
    float* ob = out + (size_t)b * (NK * ND);
    #pragma unroll
    for (int it = 0; it < 4; ++it) {
        const int idx = ck * 4096 + it * 1024 + tid * 4;
        const float sc = rinv[idx >> 10] * gi;
        float4 v = *(float4*)(ob + idx);
        v.x *= sc; v.y *= sc; v.z *= sc; v.w *= sc;
        *(float4*)(ob + idx) = v;
    }
}

extern "C" void kernel_launch(void* const* d_in, const int* in_sizes, int n_in,
                              void* d_out, int out_size, void* d_ws, size_t ws_size,
                              hipStream_t stream)
{
    const float* x    = (const float*)d_in[0];
    const float* W    = (const float*)d_in[1];
    const float* cent = (const float*)d_in[2];
    float* out = (float*)d_out;

    // ws layout: a' (8 MiB) | xb16 subtiled (128 MiB) | asum (8 KiB) | rowsq (8 KiB)
    short* aT    = (short*)d_ws;
    short* xbT   = (short*)((char*)d_ws + (size_t)NB * NM * NK * 2);
    float* asum  = (float*)((char*)d_ws + (size_t)NB * NM * NK * 2 + (size_t)NB * NM * ND * 2);
    float* rowsq = asum + NB * NK;

    hipMemsetAsync(asum, 0, 2 * NB * NK * sizeof(float), stream);

    nv1_logits_softmax<<<dim3(NM / 64, NB), 256, 0, stream>>>(x, W, aT, xbT, asum);
    nv2_vlad<<<dim3(ND / 128, NB), 512, 0, stream>>>(xbT, aT, asum, cent, out, rowsq);
    nv3_norm<<<dim3(16, NB), 256, 0, stream>>>(out, rowsq);
}

// Round 6
// 428.849 us; speedup vs baseline: 1.3069x; 1.0118x over previous
//
#include <hip/hip_runtime.h>
#include <math.h>

// NetVLAD forward, bf16-MFMA. B=32, M=2048, D=1024, K=64.
// nv1: per (b, 64-row m-tile): fused sumsq + bf16 MFMA logits + softmax
//      -> a' = softmax*invn (bf16, subtiled k-major), xb16 (bf16, subtiled 8192-elem
//         tiles, COALESCED 16B stores), asum partials (per-block slot, no atomics)
// nv2: per (b, 128-wide d-tile): vlad = a'^T · xb16 via MFMA + ds_read_b64_tr_b16;
//      gload_lds staging, 4 buffers, 3-deep counted vmcnt(6), raw s_barrier.
// nv3: intra + global normalize in place (rowsq partials summed here).

#define NB 32
#define NM 2048
#define ND 1024
#define NK 64

typedef float f32x4 __attribute__((ext_vector_type(4)));
typedef short s16x4 __attribute__((ext_vector_type(4)));
typedef short s16x8 __attribute__((ext_vector_type(8)));

static constexpr float EPS_ = 1e-12f;

__device__ __forceinline__ short f2bf(float f) {
    union { float f; unsigned u; } v; v.f = f;
    unsigned r = v.u + 0x7fffu + ((v.u >> 16) & 1u);   // RNE
    return (short)(r >> 16);
}
__device__ __forceinline__ int cvt2(float lo, float hi) {   // packed bf16 RNE
    int r; asm("v_cvt_pk_bf16_f32 %0, %1, %2" : "=v"(r) : "v"(lo), "v"(hi));
    return r;
}
__device__ __forceinline__ int4 cvt8(const float4 a, const float4 b) {
    int4 r;
    r.x = cvt2(a.x, a.y); r.y = cvt2(a.z, a.w);
    r.z = cvt2(b.x, b.y); r.w = cvt2(b.z, b.w);
    return r;
}

__device__ __forceinline__ void gload16(const void* g, void* l) {
    __builtin_amdgcn_global_load_lds(
        (const __attribute__((address_space(1))) void*)g,
        (__attribute__((address_space(3))) void*)l, 16, 0, 0);
}

// ---------------- pass 1: logits (MFMA) + softmax -> a', xb16, asum partials ----------------
__global__ __launch_bounds__(256) void nv1_logits_softmax(
    const float* __restrict__ x, const float* __restrict__ W,
    short* __restrict__ aT, short* __restrict__ xbT, float* __restrict__ asum_part)
{
    const int b = blockIdx.y, mt = blockIdx.x;
    const int tid  = threadIdx.x;
    const int w    = tid >> 6, lane = tid & 63, g = lane >> 4, c = lane & 15;
    const int wm   = w >> 1, wk = w & 1;

    __shared__ union {
        struct { short Xs[64][72]; short Ws[64][72]; } st;   // 18432 B
        float Ls[64][68];                                    // 17408 B
    } sm;
    __shared__ float red[64][8];
    __shared__ float inv_l[64];
    __shared__ float asum_l[64];

    f32x4 acc[2][2] = {};
    float sq[2] = {0.f, 0.f};

    const int r0  = tid >> 3;        // row 0..31 (and +32)
    const int dg8 = (tid & 7) << 3;  // 8-wide d group within 64-chunk
    const float* xb = x + ((size_t)b * NM + (size_t)mt * 64) * ND;
    const size_t tb = ((size_t)(b * 32 + mt) * 8) << 13;   // xb16 tile row base

    for (int d0 = 0; d0 < ND; d0 += 64) {
        __syncthreads();
        const int d    = d0 + dg8;
        const int dblk = (d >> 4) & 7;
        const size_t gpb = tb + ((size_t)(d >> 7) << 13) + (size_t)dblk * 1024 + (size_t)(d & 15);
        #pragma unroll
        for (int j = 0; j < 2; ++j) {
            const int r = r0 + 32 * j;
            const float4 xv0 = *(const float4*)(xb + (size_t)r * ND + d);
            const float4 xv1 = *(const float4*)(xb + (size_t)r * ND + d + 4);
            const float4 wv0 = *(const float4*)(W  + (size_t)r * ND + d);
            const float4 wv1 = *(const float4*)(W  + (size_t)r * ND + d + 4);
            sq[j] += xv0.x*xv0.x + xv0.y*xv0.y + xv0.z*xv0.z + xv0.w*xv0.w
                   + xv1.x*xv1.x + xv1.y*xv1.y + xv1.z*xv1.z + xv1.w*xv1.w;
            const int4 px = cvt8(xv0, xv1);
            const int4 pw = cvt8(wv0, wv1);
            *(int4*)&sm.st.Xs[r][dg8] = px;
            *(int4*)&sm.st.Ws[r][dg8] = pw;
            // coalesced subtiled store: 16B at sub=(dblk*16+(r>>2)), rr=(r&3), cc8=(d&15)
            *(int4*)(xbT + gpb + (size_t)(r >> 2) * 64 + (size_t)(r & 3) * 16) = px;
        }
        __syncthreads();
        #pragma unroll
        for (int s = 0; s < 2; ++s) {
            s16x8 af[2], bf[2];
            #pragma unroll
            for (int f = 0; f < 2; ++f) {
                af[f] = *(const s16x8*)&sm.st.Xs[wm*32 + f*16 + c][s*32 + g*8];
                bf[f] = *(const s16x8*)&sm.st.Ws[wk*32 + f*16 + c][s*32 + g*8];
            }
            #pragma unroll
            for (int fm = 0; fm < 2; ++fm)
                #pragma unroll
                for (int fk = 0; fk < 2; ++fk)
                    acc[fm][fk] = __builtin_amdgcn_mfma_f32_16x16x32_bf16(
                        af[fm], bf[fk], acc[fm][fk], 0, 0, 0);
        }
    }
    __syncthreads();
    // row-sumsq partials + logits to LDS (union region: X/W reads are done)
    red[r0][tid & 7]      = sq[0];
    red[r0 + 32][tid & 7] = sq[1];
    #pragma unroll
    for (int fm = 0; fm < 2; ++fm)
        #pragma unroll
        for (int fk = 0; fk < 2; ++fk)
            #pragma unroll
            for (int r = 0; r < 4; ++r)
                sm.Ls[wm*32 + fm*16 + g*4 + r][wk*32 + fk*16 + c] = acc[fm][fk][r];
    __syncthreads();
    if (tid < 64) {
        float s = 0.f;
        #pragma unroll
        for (int i = 0; i < 8; ++i) s += red[tid][i];
        inv_l[tid]  = 1.f / fmaxf(sqrtf(s), EPS_);
        asum_l[tid] = 0.f;
    }
    __syncthreads();

    // softmax: thread -> (row = tid>>2, 16 k's). Row spread over 4 consecutive lanes.
    const int row = tid >> 2, q = tid & 3;
    const float iv = inv_l[row];
    float e[16];
    float mx = -3.0e38f;
    #pragma unroll
    for (int j = 0; j < 16; ++j) { e[j] = sm.Ls[row][q*16 + j] * iv; mx = fmaxf(mx, e[j]); }
    mx = fmaxf(mx, __shfl_xor(mx, 1, 64));
    mx = fmaxf(mx, __shfl_xor(mx, 2, 64));
    float smv = 0.f;
    #pragma unroll
    for (int j = 0; j < 16; ++j) { e[j] = __expf(e[j] - mx); smv += e[j]; }
    smv += __shfl_xor(smv, 1, 64);
    smv += __shfl_xor(smv, 2, 64);
    const float rs = 1.f / smv;
    #pragma unroll
    for (int j = 0; j < 16; ++j) e[j] *= rs;     // plain softmax a

    // a' = a * invn, bf16, subtiled k-major: sub = (k>>4)*16 + (m>>2)
    {
        int4 p0, p1;
        p0.x = cvt2(e[0]*iv,  e[1]*iv);  p0.y = cvt2(e[2]*iv,  e[3]*iv);
        p0.z = cvt2(e[4]*iv,  e[5]*iv);  p0.w = cvt2(e[6]*iv,  e[7]*iv);
        p1.x = cvt2(e[8]*iv,  e[9]*iv);  p1.y = cvt2(e[10]*iv, e[11]*iv);
        p1.z = cvt2(e[12]*iv, e[13]*iv); p1.w = cvt2(e[14]*iv, e[15]*iv);
        const size_t base = ((size_t)(b * 32 + mt)) * 4096
                          + (size_t)(q * 16 + (row >> 2)) * 64 + (size_t)(row & 3) * 16;
        *(int4*)(aT + base)     = p0;
        *(int4*)(aT + base + 8) = p1;
    }
    // asum: reduce plain a over rows (shfl over row bits), LDS combine, per-block slot
    #pragma unroll
    for (int msk = 4; msk <= 32; msk <<= 1)
        #pragma unroll
        for (int j = 0; j < 16; ++j) e[j] += __shfl_xor(e[j], msk, 64);
    if ((tid & 60) == 0)
        #pragma unroll
        for (int j = 0; j < 16; ++j) atomicAdd(&asum_l[q*16 + j], e[j]);
    __syncthreads();
    if (tid < 64) asum_part[(size_t)(b * 32 + mt) * 64 + tid] = asum_l[tid];
}

// ---------------- pass 2: vlad = a'^T xb16 (MFMA, gload_lds, 4-buffer 3-deep) ----------------
__global__ __launch_bounds__(512) void nv2_vlad(
    const short* __restrict__ xbT, const short* __restrict__ aT,
    const float* __restrict__ asum_part, const float* __restrict__ cent,
    float* __restrict__ out, float* __restrict__ rowsq_part)
{
    const int b = blockIdx.y, dt = blockIdx.x;       // 8 d-tiles of 128
    const int tid  = threadIdx.x;
    const int w    = tid >> 6, lane = tid & 63, g = lane >> 4, c = lane & 15;
    const int wk   = w >> 2, wd = w & 3;             // 2 (k) x 4 (d) wave grid

    __shared__ short Xl[4][8192];    // 64m x 128d bf16, linear subtiled (16 KiB each)
    __shared__ short Al[4][4096];    // 64m x 64k  bf16, linear subtiled (8 KiB each)
    __shared__ float rsq_l[64];
    __shared__ float asum_s[64];

    if (tid < 64) {
        rsq_l[tid] = 0.f;
        float s = 0.f;
        const float* ap = asum_part + (size_t)b * 2048 + tid;
        #pragma unroll
        for (int j = 0; j < 32; ++j) s += ap[j * 64];
        asum_s[tid] = s;
    }

    f32x4 acc[2][2] = {};

    auto STAGE = [&](int mc, int p) {
        const short* xs  = xbT + (((size_t)(b * 32 + mc) * 8 + dt) << 13);
        const short* as_ = aT  + ((size_t)(b * 32 + mc) << 12);
        gload16(xs  + w * 1024 + lane * 8,       &Xl[p][w * 1024]);
        gload16(xs  + w * 1024 + 512 + lane * 8, &Xl[p][w * 1024 + 512]);
        gload16(as_ + w * 512 + lane * 8,        &Al[p][w * 512]);
    };

    auto COMPUTE = [&](int p) {
        const uint32_t ab_ = (uint32_t)(uintptr_t)&Al[p][0];
        const uint32_t xb_ = (uint32_t)(uintptr_t)&Xl[p][0];
        s16x4 A[2][2][2], B[2][2][2];    // [frag][kstep][half]
        #pragma unroll
        for (int f = 0; f < 2; ++f)
            #pragma unroll
            for (int s = 0; s < 2; ++s)
                #pragma unroll
                for (int r = 0; r < 2; ++r) {
                    const uint32_t srow = (uint32_t)(s*8 + g*2 + r);
                    const uint32_t aoff = ab_ + (((uint32_t)(wk*2 + f)*16u + srow)*128u) + (uint32_t)c*8u;
                    const uint32_t boff = xb_ + (((uint32_t)(wd*2 + f)*16u + srow)*128u) + (uint32_t)c*8u;
                    asm volatile("ds_read_b64_tr_b16 %0, %1" : "=v"(A[f][s][r]) : "v"(aoff));
                    asm volatile("ds_read_b64_tr_b16 %0, %1" : "=v"(B[f][s][r]) : "v"(boff));
                }
        asm volatile("s_waitcnt lgkmcnt(0)" ::: "memory");
        __builtin_amdgcn_sched_barrier(0);
        #pragma unroll
        for (int s = 0; s < 2; ++s)
            #pragma unroll
            for (int fk = 0; fk < 2; ++fk) {
                const s16x8 af = __builtin_shufflevector(A[fk][s][0], A[fk][s][1], 0,1,2,3,4,5,6,7);
                #pragma unroll
                for (int fd = 0; fd < 2; ++fd) {
                    const s16x8 bf = __builtin_shufflevector(B[fd][s][0], B[fd][s][1], 0,1,2,3,4,5,6,7);
                    acc[fk][fd] = __builtin_amdgcn_mfma_f32_16x16x32_bf16(af, bf, acc[fk][fd], 0, 0, 0);
                }
            }
    };

    // prologue: fill 3 buffers, keep them in flight (T4: counted vmcnt, raw barrier)
    STAGE(0, 0);
    STAGE(1, 1);
    STAGE(2, 2);
    for (int mc = 0; mc < 32; ++mc) {
        // wait for chunk mc's 3 loads; up to 6 newer (chunks mc+1, mc+2) stay in flight
        if (mc < 30)      asm volatile("s_waitcnt vmcnt(6)" ::: "memory");
        else if (mc == 30) asm volatile("s_waitcnt vmcnt(3)" ::: "memory");
        else              asm volatile("s_waitcnt vmcnt(0)" ::: "memory");
        __builtin_amdgcn_s_barrier();
        if (mc + 3 < 32) STAGE(mc + 3, (mc + 3) & 3);   // buffer (mc-1)&3: fully read last iter
        COMPUTE(mc & 3);
    }

    // epilogue: subtract asum*cent, write out, accumulate rowsq
    const float* cb = cent + (size_t)dt * 128;
    #pragma unroll
    for (int fk = 0; fk < 2; ++fk)
        #pragma unroll
        for (int r = 0; r < 4; ++r) {
            const int k = wk*32 + fk*16 + g*4 + r;
            const float as = asum_s[k];
            float s2 = 0.f;
            #pragma unroll
            for (int fd = 0; fd < 2; ++fd) {
                const int d = wd*32 + fd*16 + c;
                const float v = acc[fk][fd][r] - as * cb[(size_t)k * ND + d];
                out[((size_t)b * 64 + k) * ND + (size_t)dt * 128 + d] = v;
                s2 += v * v;
            }
            s2 += __shfl_xor(s2, 1, 64);
            s2 += __shfl_xor(s2, 2, 64);
            s2 += __shfl_xor(s2, 4, 64);
            s2 += __shfl_xor(s2, 8, 64);
            if (c == 0) atomicAdd(&rsq_l[k], s2);
        }
    __syncthreads();
    if (tid < 64) rowsq_part[(size_t)(b * 8 + dt) * 64 + tid] = rsq_l[tid];
}

// ---------------- pass 3: intra + global normalize (in place) ----------------
__global__ __launch_bounds__(256) void nv3_norm(
    float* __restrict__ out, const float* __restrict__ rowsq_part)
{
    const int b = blockIdx.y, ck = blockIdx.x;
    const int tid = threadIdx.x;
    __shared__ float rinv[64];
    __shared__ float gred[64];
    __shared__ float ginv_s;
    if (tid < 64) {
        float rs = 0.f;
        const float* rp = rowsq_part + (size_t)b * 512 + tid;
        #pragma unroll
        for (int j = 0; j < 8; ++j) rs += rp[j * 64];
        const float n = fmaxf(sqrtf(rs), EPS_);
        rinv[tid] = 1.f / n;
        gred[tid] = (rs / n) / n;
    }
    __syncthreads();
    if (tid == 0) {
        float s = 0.f;
        for (int k = 0; k < 64; ++k) s += gred[k];
        ginv_s = 1.f / fmaxf(sqrtf(s), EPS_);
    }
    __syncthreads();
    const float gi = ginv_s;
    float* ob = out + (size_t)b * (NK * ND);
    #pragma unroll
    for (int it = 0; it < 4; ++it) {
        const int idx = ck * 4096 + it * 1024 + tid * 4;
        const float sc = rinv[idx >> 10] * gi;
        float4 v = *(float4*)(ob + idx);
        v.x *= sc; v.y *= sc; v.z *= sc; v.w *= sc;
        *(float4*)(ob + idx) = v;
    }
}

extern "C" void kernel_launch(void* const* d_in, const int* in_sizes, int n_in,
                              void* d_out, int out_size, void* d_ws, size_t ws_size,
                              hipStream_t stream)
{
    const float* x    = (const float*)d_in[0];
    const float* W    = (const float*)d_in[1];
    const float* cent = (const float*)d_in[2];
    float* out = (float*)d_out;

    // ws: a' (8 MiB) | xb16 (128 MiB) | asum_part (256 KiB) | rowsq_part (64 KiB)
    short* aT         = (short*)d_ws;
    short* xbT        = (short*)((char*)d_ws + (size_t)NB * NM * NK * 2);
    float* asum_part  = (float*)((char*)d_ws + (size_t)NB * NM * NK * 2 + (size_t)NB * NM * ND * 2);
    float* rowsq_part = asum_part + NB * 32 * 64;

    nv1_logits_softmax<<<dim3(NM / 64, NB), 256, 0, stream>>>(x, W, aT, xbT, asum_part);
    nv2_vlad<<<dim3(ND / 128, NB), 512, 0, stream>>>(xbT, aT, asum_part, cent, out, rowsq_part);
    nv3_norm<<<dim3(16, NB), 256, 0, stream>>>(out, rowsq_part);
}

// Round 7
// 427.433 us; speedup vs baseline: 1.3112x; 1.0033x over previous
//
#include <hip/hip_runtime.h>
#include <math.h>

// NetVLAD forward, FUSED bf16-MFMA. B=32, M=2048, D=1024, K=64.
// nv_fused: block = (b, pb) owns 256 m rows. Per 64-row chunk:
//   phase A: stage x->LDS xk (bf16, subtiled) + W->LDS dbuf, logits MFMA, fused sumsq
//   softmax (logits in Ws-union scratch) -> a_tile (bf16 subtiled LDS) + asum_l
//   phase B: vlad acc (64k x 1024d, 128 AGPR/lane over 8 waves) += a_tile^T * xk
//            via ds_read_b64_tr_b16 + MFMA  (same formulas as the verified R6 nv2)
// epilogue: write 256KB f32 partial + asum partial (per-block slots, no atomics).
// nv_reduce: per (b, 128-d tile): sum 8 partials - asum*cent -> out raw + rowsq_part.
// nv3: intra + global normalize in place.

#define NB 32
#define NM 2048
#define ND 1024
#define NK 64

typedef float f32x4 __attribute__((ext_vector_type(4)));
typedef short s16x4 __attribute__((ext_vector_type(4)));
typedef short s16x8 __attribute__((ext_vector_type(8)));

static constexpr float EPS_ = 1e-12f;

__device__ __forceinline__ int cvt2(float lo, float hi) {   // packed bf16 RNE
    int r; asm("v_cvt_pk_bf16_f32 %0, %1, %2" : "=v"(r) : "v"(lo), "v"(hi));
    return r;
}
__device__ __forceinline__ int4 cvt8(const float4 a, const float4 b) {
    int4 r;
    r.x = cvt2(a.x, a.y); r.y = cvt2(a.z, a.w);
    r.z = cvt2(b.x, b.y); r.w = cvt2(b.z, b.w);
    return r;
}

struct SMem {
    short xk[65536];                                  // 128 KiB: 64m x 1024d bf16, subtiled per 128-d tile
    union { short Ws[2][64][72]; float Ls[64][68]; } u;  // 18432 B: W staging dbuf / logits scratch
    short at[4096];                                   // 8 KiB: 64m x 64k bf16, subtiled k-major
    float red[64][8];
    float inv_l[64];
    float asum_l[64];
};  // total 160256 B <= 163840

// ---------------- fused pass ----------------
__global__ __launch_bounds__(512, 2) void nv_fused(
    const float* __restrict__ x, const float* __restrict__ W,
    float* __restrict__ part, float* __restrict__ asum_part)
{
    __shared__ SMem sm;
    const int b = blockIdx.y, pb = blockIdx.x;
    const int tid  = threadIdx.x;
    const int w    = tid >> 6, lane = tid & 63, g = lane >> 4, c = lane & 15;
    const int wm   = w >> 2, wk = w & 3;     // phase A wave grid: 2(m) x 4(k)
    const int row  = tid >> 3, q = tid & 7;  // staging / softmax mapping

    if (tid < 64) sm.asum_l[tid] = 0.f;

    f32x4 vacc[4][8] = {};   // phase B acc: 4 k-frags x 8 d-frags (this wave's 128-d tile)

    const uint32_t xkb = (uint32_t)(uintptr_t)&sm.xk[0];
    const uint32_t atb = (uint32_t)(uintptr_t)&sm.at[0];

    for (int mc = 0; mc < 4; ++mc) {
        const size_t xrow = ((size_t)b * NM + (size_t)pb * 256 + mc * 64 + row) * ND;
        f32x4 lacc[2] = {};
        float sq = 0.f;

        // lambda: logits MFMA for d-chunk tt (reads Ws[tt&1] + xk region tt)
        auto A_MFMA = [&](int tt) {
            #pragma unroll
            for (int s = 0; s < 2; ++s) {
                const int dd   = tt * 64 + s * 32 + g * 8;
                const int dtl  = dd >> 7, dblk = (dd >> 4) & 7, dlo = dd & 15;
                const s16x8 bfr = *(const s16x8*)&sm.u.Ws[tt & 1][wk * 16 + c][s * 32 + g * 8];
                #pragma unroll
                for (int f = 0; f < 2; ++f) {
                    const int m = wm * 32 + f * 16 + c;
                    const s16x8 afr = *(const s16x8*)&sm.xk[dtl * 8192
                        + (dblk * 16 + (m >> 2)) * 64 + (m & 3) * 16 + dlo];
                    lacc[f] = __builtin_amdgcn_mfma_f32_16x16x32_bf16(afr, bfr, lacc[f], 0, 0, 0);
                }
            }
        };

        // ---- phase A: 16 d-chunks of 64 ----
        for (int t = 0; t < 16; ++t) {
            const int d = t * 64 + q * 8;
            const float4 xv0 = *(const float4*)(x + xrow + d);
            const float4 xv1 = *(const float4*)(x + xrow + d + 4);
            const float4 wv0 = *(const float4*)(W + (size_t)row * ND + d);
            const float4 wv1 = *(const float4*)(W + (size_t)row * ND + d + 4);
            if (t > 0) A_MFMA(t - 1);       // overlap MFMA(t-1) with loads(t) in flight
            sq += xv0.x*xv0.x + xv0.y*xv0.y + xv0.z*xv0.z + xv0.w*xv0.w
                + xv1.x*xv1.x + xv1.y*xv1.y + xv1.z*xv1.z + xv1.w*xv1.w;
            const int4 px = cvt8(xv0, xv1);
            const int4 pw = cvt8(wv0, wv1);
            const int dblk = (d >> 4) & 7;
            *(int4*)&sm.xk[(d >> 7) * 8192 + (dblk * 16 + (row >> 2)) * 64
                           + (row & 3) * 16 + (d & 15)] = px;
            *(int4*)&sm.u.Ws[t & 1][row][q * 8] = pw;
            __syncthreads();
        }
        A_MFMA(15);
        sm.red[row][q] = sq;
        __syncthreads();                     // all Ws reads done -> union reuse as Ls

        #pragma unroll
        for (int f = 0; f < 2; ++f)
            #pragma unroll
            for (int r = 0; r < 4; ++r)
                sm.u.Ls[wm * 32 + f * 16 + g * 4 + r][wk * 16 + c] = lacc[f][r];
        if (tid < 64) {
            float s = 0.f;
            #pragma unroll
            for (int i = 0; i < 8; ++i) s += sm.red[tid][i];
            sm.inv_l[tid] = 1.f / fmaxf(sqrtf(s), EPS_);
        }
        __syncthreads();

        // ---- softmax: thread (row, q) owns 8 k = q*8..q*8+7 ----
        {
            const float iv = sm.inv_l[row];
            float e[8];
            float mx = -3.0e38f;
            #pragma unroll
            for (int j = 0; j < 8; ++j) { e[j] = sm.u.Ls[row][q * 8 + j] * iv; mx = fmaxf(mx, e[j]); }
            mx = fmaxf(mx, __shfl_xor(mx, 1, 64));
            mx = fmaxf(mx, __shfl_xor(mx, 2, 64));
            mx = fmaxf(mx, __shfl_xor(mx, 4, 64));
            float sv = 0.f;
            #pragma unroll
            for (int j = 0; j < 8; ++j) { e[j] = __expf(e[j] - mx); sv += e[j]; }
            sv += __shfl_xor(sv, 1, 64);
            sv += __shfl_xor(sv, 2, 64);
            sv += __shfl_xor(sv, 4, 64);
            const float rs = 1.f / sv;
            #pragma unroll
            for (int j = 0; j < 8; ++j) e[j] *= rs;          // plain softmax a
            int4 av;
            av.x = cvt2(e[0]*iv, e[1]*iv); av.y = cvt2(e[2]*iv, e[3]*iv);
            av.z = cvt2(e[4]*iv, e[5]*iv); av.w = cvt2(e[6]*iv, e[7]*iv);
            // a' subtiled k-major: sub=(k>>4)*16+(m>>2), off=(m&3)*16+(k&15)
            *(int4*)&sm.at[((q >> 1) * 16 + (row >> 2)) * 64 + (row & 3) * 16 + (q & 1) * 8] = av;
            // asum partial: reduce over the wave's 8 rows, one lane-set adds
            #pragma unroll
            for (int j = 0; j < 8; ++j) {
                e[j] += __shfl_xor(e[j], 8, 64);
                e[j] += __shfl_xor(e[j], 16, 64);
                e[j] += __shfl_xor(e[j], 32, 64);
            }
            if ((lane >> 3) == 0)
                #pragma unroll
                for (int j = 0; j < 8; ++j) atomicAdd(&sm.asum_l[q * 8 + j], e[j]);
        }
        __syncthreads();                     // a_tile + xk ready for phase B

        // ---- phase B: vacc += a_tile^T * xk (this wave's 128-d tile) ----
        #pragma unroll
        for (int s = 0; s < 2; ++s) {
            s16x4 A[4][2], Bf[8][2];
            #pragma unroll
            for (int kf = 0; kf < 4; ++kf)
                #pragma unroll
                for (int r = 0; r < 2; ++r) {
                    const uint32_t srow = (uint32_t)(s * 8 + g * 2 + r);
                    const uint32_t aoff = atb + ((uint32_t)kf * 16u + srow) * 128u + (uint32_t)c * 8u;
                    asm volatile("ds_read_b64_tr_b16 %0, %1" : "=v"(A[kf][r]) : "v"(aoff));
                }
            #pragma unroll
            for (int fd = 0; fd < 8; ++fd)
                #pragma unroll
                for (int r = 0; r < 2; ++r) {
                    const uint32_t srow = (uint32_t)(s * 8 + g * 2 + r);
                    const uint32_t boff = xkb + (uint32_t)w * 16384u
                                        + ((uint32_t)fd * 16u + srow) * 128u + (uint32_t)c * 8u;
                    asm volatile("ds_read_b64_tr_b16 %0, %1" : "=v"(Bf[fd][r]) : "v"(boff));
                }
            asm volatile("s_waitcnt lgkmcnt(0)" ::: "memory");
            __builtin_amdgcn_sched_barrier(0);
            #pragma unroll
            for (int kf = 0; kf < 4; ++kf) {
                const s16x8 af = __builtin_shufflevector(A[kf][0], A[kf][1], 0,1,2,3,4,5,6,7);
                #pragma unroll
                for (int fd = 0; fd < 8; ++fd) {
                    const s16x8 bf = __builtin_shufflevector(Bf[fd][0], Bf[fd][1], 0,1,2,3,4,5,6,7);
                    vacc[kf][fd] = __builtin_amdgcn_mfma_f32_16x16x32_bf16(af, bf, vacc[kf][fd], 0, 0, 0);
                }
            }
        }
        __syncthreads();                     // protect xk/at before next chunk restage
    }

    // ---- epilogue: write partial vlad + asum partial ----
    float* pbase = part + (((size_t)(b * 8 + pb)) << 16);   // 64*1024 floats per slot
    #pragma unroll
    for (int kf = 0; kf < 4; ++kf)
        #pragma unroll
        for (int r = 0; r < 4; ++r) {
            const int k = kf * 16 + g * 4 + r;
            #pragma unroll
            for (int fd = 0; fd < 8; ++fd)
                pbase[(size_t)k * ND + w * 128 + fd * 16 + c] = vacc[kf][fd][r];
        }
    if (tid < 64) asum_part[(b * 8 + pb) * 64 + tid] = sm.asum_l[tid];
}

// ---------------- reduce: sum partials - asum*cent -> out raw + rowsq ----------------
__global__ __launch_bounds__(256) void nv_reduce(
    const float* __restrict__ part, const float* __restrict__ asum_part,
    const float* __restrict__ cent, float* __restrict__ out, float* __restrict__ rowsq_part)
{
    const int b = blockIdx.y, dt = blockIdx.x;   // 8 d-tiles of 128
    const int tid = threadIdx.x;
    __shared__ float asum_s[64];
    if (tid < 64) {
        float s = 0.f;
        #pragma unroll
        for (int pbi = 0; pbi < 8; ++pbi) s += asum_part[(b * 8 + pbi) * 64 + tid];
        asum_s[tid] = s;
    }
    __syncthreads();
    const int dq = (tid & 31) * 4;       // d within 128-slice
    const int kb = (tid >> 5) * 8;       // 8 k rows per thread group
    float s2[8];
    #pragma unroll
    for (int kk = 0; kk < 8; ++kk) {
        const int k = kb + kk;
        float4 acc = make_float4(0.f, 0.f, 0.f, 0.f);
        #pragma unroll
        for (int pbi = 0; pbi < 8; ++pbi) {
            const float4 p = *(const float4*)(part + (((size_t)(b * 8 + pbi)) << 16)
                                              + (size_t)k * ND + dt * 128 + dq);
            acc.x += p.x; acc.y += p.y; acc.z += p.z; acc.w += p.w;
        }
        const float as = asum_s[k];
        const float4 cv = *(const float4*)(cent + (size_t)k * ND + dt * 128 + dq);
        float4 v;
        v.x = acc.x - as * cv.x; v.y = acc.y - as * cv.y;
        v.z = acc.z - as * cv.z; v.w = acc.w - as * cv.w;
        *(float4*)(out + ((size_t)b * NK + k) * ND + dt * 128 + dq) = v;
        s2[kk] = v.x*v.x + v.y*v.y + v.z*v.z + v.w*v.w;
    }
    #pragma unroll
    for (int kk = 0; kk < 8; ++kk) {
        s2[kk] += __shfl_xor(s2[kk], 1, 64);
        s2[kk] += __shfl_xor(s2[kk], 2, 64);
        s2[kk] += __shfl_xor(s2[kk], 4, 64);
        s2[kk] += __shfl_xor(s2[kk], 8, 64);
        s2[kk] += __shfl_xor(s2[kk], 16, 64);
    }
    if ((tid & 31) == 0)
        #pragma unroll
        for (int kk = 0; kk < 8; ++kk)
            rowsq_part[(b * 8 + dt) * 64 + kb + kk] = s2[kk];
}

// ---------------- pass 3: intra + global normalize (in place) ----------------
__global__ __launch_bounds__(256) void nv3_norm(
    float* __restrict__ out, const float* __restrict__ rowsq_part)
{
    const int b = blockIdx.y, ck = blockIdx.x;
    const int tid = threadIdx.x;
    __shared__ float rinv[64];
    __shared__ float gred[64];
    __shared__ float ginv_s;
    if (tid < 64) {
        float rs = 0.f;
        const float* rp = rowsq_part + (size_t)b * 512 + tid;
        #pragma unroll
        for (int j = 0; j < 8; ++j) rs += rp[j * 64];
        const float n = fmaxf(sqrtf(rs), EPS_);
        rinv[tid] = 1.f / n;
        gred[tid] = (rs / n) / n;
    }
    __syncthreads();
    if (tid == 0) {
        float s = 0.f;
        for (int k = 0; k < 64; ++k) s += gred[k];
        ginv_s = 1.f / fmaxf(sqrtf(s), EPS_);
    }
    __syncthreads();
    const float gi = ginv_s;
    float* ob = out + (size_t)b * (NK * ND);
    #pragma unroll
    for (int it = 0; it < 4; ++it) {
        const int idx = ck * 4096 + it * 1024 + tid * 4;
        const float sc = rinv[idx >> 10] * gi;
        float4 v = *(float4*)(ob + idx);
        v.x *= sc; v.y *= sc; v.z *= sc; v.w *= sc;
        *(float4*)(ob + idx) = v;
    }
}

extern "C" void kernel_launch(void* const* d_in, const int* in_sizes, int n_in,
                              void* d_out, int out_size, void* d_ws, size_t ws_size,
                              hipStream_t stream)
{
    const float* x    = (const float*)d_in[0];
    const float* W    = (const float*)d_in[1];
    const float* cent = (const float*)d_in[2];
    float* out = (float*)d_out;

    // ws: part (64 MiB: 256 slots x 64x1024 f32) | asum_part (64 KiB) | rowsq_part (64 KiB)
    float* part       = (float*)d_ws;
    float* asum_part  = (float*)((char*)d_ws + ((size_t)256 << 18));
    float* rowsq_part = asum_part + 256 * 64;

    nv_fused<<<dim3(8, NB), 512, 0, stream>>>(x, W, part, asum_part);
    nv_reduce<<<dim3(8, NB), 256, 0, stream>>>(part, asum_part, cent, out, rowsq_part);
    nv3_norm<<<dim3(16, NB), 256, 0, stream>>>(out, rowsq_part);
}